// Round 1
// baseline (42.204 us; speedup 1.0000x reference)
//
#include <hip/hip_runtime.h>
#include <math.h>

// ---------------- problem constants ----------------
#define NCLS 80
#define BSZ  16
#define NTGT 32
#define KNEG 1000
#define NO   (6 + NCLS)   // 86 channels per cell

#define NPOS (3 * BSZ * NTGT)        // 1536
#define NNEG (3 * BSZ * KNEG)        // 48000
#define NITEMS (NPOS + NNEG)         // 49536

#define L_BOX 0.05f
#define L_OBJ 1.0f
#define L_CLS 0.5f

#define PI_F   3.14159265358979323846f
#define TWOPI_F 6.28318530717958647692f

__constant__ float c_anchors[3][3][2] = {
    {{10.f, 13.f}, {16.f, 30.f}, {33.f, 23.f}},
    {{30.f, 61.f}, {62.f, 45.f}, {59.f, 119.f}},
    {{116.f, 90.f}, {156.f, 198.f}, {373.f, 326.f}}
};

__device__ __forceinline__ float softplus_f(float x) {
    // stable: max(x,0) + log1p(exp(-|x|))  == log(1+e^x)
    return fmaxf(x, 0.f) + log1pf(expf(-fabsf(x)));
}

__device__ __forceinline__ float smooth_l1(float d) {
    float a = fabsf(d);
    return (a < 1.f) ? (0.5f * a * a) : (a - 0.5f);
}

__global__ void zero_out_kernel(float* out) {
    out[0] = 0.f;
}

__global__ void yolo_loss_kernel(
    const float* __restrict__ p0, const float* __restrict__ p1, const float* __restrict__ p2,
    const int* __restrict__ ri0, const int* __restrict__ rj0, const int* __restrict__ rk0,
    const int* __restrict__ ri1, const int* __restrict__ rj1, const int* __restrict__ rk1,
    const int* __restrict__ ri2, const int* __restrict__ rj2, const int* __restrict__ rk2,
    const float* __restrict__ boxes,   // (BSZ, NTGT, 5)
    const int*  __restrict__ labels,   // (BSZT, NTGT)
    const int*  __restrict__ strides,  // (3,)
    float* __restrict__ out)
{
    float local = 0.f;

    const int gid     = blockIdx.x * blockDim.x + threadIdx.x;
    const int gstride = gridDim.x * blockDim.x;

    for (int idx = gid; idx < NITEMS; idx += gstride) {
        if (idx < NPOS) {
            // ---------------- positive target ----------------
            const int l   = idx >> 9;        // / (BSZ*NTGT) = /512
            const int rem = idx & 511;
            const int b   = rem >> 5;        // /NTGT
            const int t   = rem & 31;

            int h, w;
            const float* p;
            if (l == 0)      { h = 80; w = 80; p = p0; }
            else if (l == 1) { h = 40; w = 40; p = p1; }
            else             { h = 20; w = 20; p = p2; }

            const float s = (float)strides[l];

            const float* bx = boxes + ((size_t)b * NTGT + t) * 5;
            const float gx = bx[0] / s;
            const float gy = bx[1] / s;
            const float gw = bx[2] / s;
            const float gh = bx[3] / s;
            const float ta = bx[4];

            // best anchor: argmin over a of max aspect ratio (first-min tie-break)
            int   best    = 0;
            float best_ar = 1e30f;
            #pragma unroll
            for (int a = 0; a < 3; ++a) {
                const float ax = c_anchors[l][a][0] / s;
                const float ay = c_anchors[l][a][1] / s;
                const float rx = gw / ax;
                const float ry = gh / ay;
                const float arx = fmaxf(rx, 1.f / rx);
                const float ary = fmaxf(ry, 1.f / ry);
                const float ar  = fmaxf(arx, ary);
                if (ar < best_ar) { best_ar = ar; best = a; }
            }

            // grid cell (truncate toward zero like astype(int32), then clip)
            int gi = (int)gx; gi = min(max(gi, 0), w - 1);
            int gj = (int)gy; gj = min(max(gj, 0), h - 1);

            const float* sel = p + ((((size_t)b * 3 + best) * h + gj) * w + gi) * NO;

            const float px   = sel[0];
            const float py   = sel[1];
            const float pw   = sel[2];
            const float ph   = sel[3];
            const float pa   = sel[4];
            const float pobj = sel[5];

            const float tx = gx - (float)gi;
            const float ty = gy - (float)gj;

            const float abx = c_anchors[l][best][0] / s;
            const float aby = c_anchors[l][best][1] / s;
            float tw_t = logf(gw / abx + 1e-6f);
            tw_t = fminf(fmaxf(tw_t, -4.f), 4.f);
            float th_t = logf(gh / aby + 1e-6f);
            th_t = fminf(fmaxf(th_t, -4.f), 4.f);

            // jnp.remainder(v, 2pi) - pi  (floor-mod, result in [0,2pi))
            const float v = pa - ta + PI_F;
            float m = v - floorf(v / TWOPI_F) * TWOPI_F;
            const float ang = m - PI_F;

            float box = smooth_l1(px - tx)
                      + smooth_l1(py - ty)
                      + smooth_l1(fminf(fmaxf(pw, -4.f), 4.f) - tw_t)
                      + smooth_l1(fminf(fmaxf(ph, -4.f), 4.f) - th_t)
                      + smooth_l1(ang);

            // obj with target 1: softplus(x) - x
            float obj = softplus_f(pobj) - pobj;

            // cls: sum_c softplus(x_c) - x_c * [c==label]
            const int lab = labels[b * NTGT + t];
            float cls = 0.f;
            for (int c = 0; c < NCLS; ++c) {
                const float x = sel[6 + c];
                cls += softplus_f(x);
                if (c == lab) cls -= x;
            }

            local += L_BOX * box + L_OBJ * obj + L_CLS * cls;
        } else {
            // ---------------- negative obj sample ----------------
            const int n   = idx - NPOS;
            const int l   = n / (BSZ * KNEG);
            const int rem = n % (BSZ * KNEG);
            const int b   = rem / KNEG;
            const int k   = rem % KNEG;

            int h, w;
            const float* p;
            const int *ri, *rj, *rk;
            if (l == 0)      { h = 80; w = 80; p = p0; ri = ri0; rj = rj0; rk = rk0; }
            else if (l == 1) { h = 40; w = 40; p = p1; ri = ri1; rj = rj1; rk = rk1; }
            else             { h = 20; w = 20; p = p2; ri = ri2; rj = rj2; rk = rk2; }

            const int a  = ri[b * KNEG + k];
            const int jj = rj[b * KNEG + k];
            const int kk = rk[b * KNEG + k];

            const float x = p[((((size_t)b * 3 + a) * h + jj) * w + kk) * NO + 5];
            // bce with target 0: softplus(x)
            local += L_OBJ * softplus_f(x);
        }
    }

    // ---- wave (64-lane) reduction ----
    #pragma unroll
    for (int off = 32; off > 0; off >>= 1)
        local += __shfl_down(local, off, 64);

    __shared__ float wave_sum[4];   // 256 threads / 64
    const int lane = threadIdx.x & 63;
    const int wid  = threadIdx.x >> 6;
    if (lane == 0) wave_sum[wid] = local;
    __syncthreads();

    if (threadIdx.x == 0) {
        float s = 0.f;
        const int nw = (blockDim.x + 63) >> 6;
        for (int i = 0; i < nw; ++i) s += wave_sum[i];
        atomicAdd(out, s);
    }
}

extern "C" void kernel_launch(void* const* d_in, const int* in_sizes, int n_in,
                              void* d_out, int out_size, void* d_ws, size_t ws_size,
                              hipStream_t stream) {
    // setup_inputs() dict order:
    // p0, ri0, rj0, rk0, p1, ri1, rj1, rk1, p2, ri2, rj2, rk2, boxes, labels, strides
    const float* p0 = (const float*)d_in[0];
    const int* ri0  = (const int*)d_in[1];
    const int* rj0  = (const int*)d_in[2];
    const int* rk0  = (const int*)d_in[3];
    const float* p1 = (const float*)d_in[4];
    const int* ri1  = (const int*)d_in[5];
    const int* rj1  = (const int*)d_in[6];
    const int* rk1  = (const int*)d_in[7];
    const float* p2 = (const float*)d_in[8];
    const int* ri2  = (const int*)d_in[9];
    const int* rj2  = (const int*)d_in[10];
    const int* rk2  = (const int*)d_in[11];
    const float* boxes  = (const float*)d_in[12];
    const int* labels   = (const int*)d_in[13];
    const int* strides  = (const int*)d_in[14];
    float* out = (float*)d_out;

    zero_out_kernel<<<1, 1, 0, stream>>>(out);

    const int threads = 256;
    const int blocks  = (NITEMS + threads - 1) / threads;   // 194
    yolo_loss_kernel<<<blocks, threads, 0, stream>>>(
        p0, p1, p2,
        ri0, rj0, rk0, ri1, rj1, rk1, ri2, rj2, rk2,
        boxes, labels, strides, out);
}

// Round 2
// 11.520 us; speedup vs baseline: 3.6635x; 3.6635x over previous
//
#include <hip/hip_runtime.h>
#include <math.h>

// ---------------- problem constants ----------------
#define NCLS 80
#define BSZ  16
#define NTGT 32
#define KNEG 1000
#define NO   (6 + NCLS)   // 86 channels per cell

#define NPOS   (3 * BSZ * NTGT)      // 1536
#define NNEG   (3 * BSZ * KNEG)     // 48000
#define NCLSI  (NPOS * NCLS)        // 122880 : one thread per (positive, class)
#define NTOT   (NCLSI + NNEG + NPOS) // 172416

#define THREADS 256
#define BLOCKS  ((NTOT + THREADS - 1) / THREADS)   // 674

#define L_BOX 0.05f
#define L_OBJ 1.0f
#define L_CLS 0.5f

#define PI_F    3.14159265358979323846f
#define TWOPI_F 6.28318530717958647692f

__constant__ float c_anchors[3][3][2] = {
    {{10.f, 13.f}, {16.f, 30.f}, {33.f, 23.f}},
    {{30.f, 61.f}, {62.f, 45.f}, {59.f, 119.f}},
    {{116.f, 90.f}, {156.f, 198.f}, {373.f, 326.f}}
};

__device__ __forceinline__ float softplus_f(float x) {
    // stable: max(x,0) + log1p(exp(-|x|)) == log(1+e^x)
    return fmaxf(x, 0.f) + log1pf(expf(-fabsf(x)));
}

__device__ __forceinline__ float smooth_l1(float d) {
    float a = fabsf(d);
    return (a < 1.f) ? (0.5f * a * a) : (a - 0.5f);
}

struct Cell {
    const float* sel;   // base of the 86-channel cell
    float gx, gy, gw, gh, ta, s;
    int gi, gj, best, l, b, t;
};

__device__ __forceinline__ Cell decode_cell(int pos,
    const float* __restrict__ p0, const float* __restrict__ p1, const float* __restrict__ p2,
    const float* __restrict__ boxes, const int* __restrict__ strides)
{
    Cell c;
    c.l = pos >> 9;              // / (BSZ*NTGT)
    const int rem = pos & 511;
    c.b = rem >> 5;
    c.t = rem & 31;

    int h, w; const float* p;
    if (c.l == 0)      { h = 80; w = 80; p = p0; }
    else if (c.l == 1) { h = 40; w = 40; p = p1; }
    else               { h = 20; w = 20; p = p2; }

    c.s = (float)strides[c.l];

    const float* bx = boxes + ((size_t)c.b * NTGT + c.t) * 5;
    c.gx = bx[0] / c.s;
    c.gy = bx[1] / c.s;
    c.gw = bx[2] / c.s;
    c.gh = bx[3] / c.s;
    c.ta = bx[4];

    // best anchor: argmin over a of max aspect ratio (strict <, first-min tie-break)
    int best = 0; float best_ar = 1e30f;
    #pragma unroll
    for (int a = 0; a < 3; ++a) {
        const float ax = c_anchors[c.l][a][0] / c.s;
        const float ay = c_anchors[c.l][a][1] / c.s;
        const float rx = c.gw / ax;
        const float ry = c.gh / ay;
        const float ar = fmaxf(fmaxf(rx, 1.f / rx), fmaxf(ry, 1.f / ry));
        if (ar < best_ar) { best_ar = ar; best = a; }
    }
    c.best = best;

    // truncate toward zero like astype(int32), then clip
    c.gi = min(max((int)c.gx, 0), w - 1);
    c.gj = min(max((int)c.gy, 0), h - 1);

    c.sel = p + ((((size_t)c.b * 3 + best) * h + c.gj) * w + c.gi) * NO;
    return c;
}

__global__ __launch_bounds__(THREADS)
void yolo_main_kernel(
    const float* __restrict__ p0, const float* __restrict__ p1, const float* __restrict__ p2,
    const int* __restrict__ ri0, const int* __restrict__ rj0, const int* __restrict__ rk0,
    const int* __restrict__ ri1, const int* __restrict__ rj1, const int* __restrict__ rk1,
    const int* __restrict__ ri2, const int* __restrict__ rj2, const int* __restrict__ rk2,
    const float* __restrict__ boxes,   // (BSZ, NTGT, 5)
    const int*  __restrict__ labels,   // (BSZ, NTGT)
    const int*  __restrict__ strides,  // (3,)
    float* __restrict__ partials)      // (BLOCKS,)
{
    const int idx = blockIdx.x * blockDim.x + threadIdx.x;
    float local = 0.f;

    if (idx < NCLSI) {
        // ------- class BCE: one thread per (positive, class) -------
        const int pos = idx / NCLS;          // compiler magic-mul
        const int cc  = idx - pos * NCLS;
        Cell c = decode_cell(pos, p0, p1, p2, boxes, strides);
        const int lab = labels[c.b * NTGT + c.t];
        const float x = c.sel[6 + cc];       // 80 consecutive threads -> coalesced
        float v = softplus_f(x);
        if (cc == lab) v -= x;
        local = L_CLS * v;
    } else if (idx < NCLSI + NNEG) {
        // ------- negative obj sample -------
        const int n   = idx - NCLSI;
        const int l   = n / (BSZ * KNEG);
        const int rem = n - l * (BSZ * KNEG);
        const int bk  = rem;                 // b*KNEG + k

        int h, w; const float* p; const int *ri, *rj, *rk;
        if (l == 0)      { h = 80; w = 80; p = p0; ri = ri0; rj = rj0; rk = rk0; }
        else if (l == 1) { h = 40; w = 40; p = p1; ri = ri1; rj = rj1; rk = rk1; }
        else             { h = 20; w = 20; p = p2; ri = ri2; rj = rj2; rk = rk2; }

        const int b  = bk / KNEG;
        const int a  = ri[bk];
        const int jj = rj[bk];
        const int kk = rk[bk];

        const float x = p[((((size_t)b * 3 + a) * h + jj) * w + kk) * NO + 5];
        local = L_OBJ * softplus_f(x);       // bce target 0
    } else if (idx < NTOT) {
        // ------- positive box + obj -------
        const int pos = idx - (NCLSI + NNEG);
        Cell c = decode_cell(pos, p0, p1, p2, boxes, strides);

        const float px   = c.sel[0];
        const float py   = c.sel[1];
        const float pw   = c.sel[2];
        const float ph   = c.sel[3];
        const float pa   = c.sel[4];
        const float pobj = c.sel[5];

        const float tx = c.gx - (float)c.gi;
        const float ty = c.gy - (float)c.gj;

        const float abx = c_anchors[c.l][c.best][0] / c.s;
        const float aby = c_anchors[c.l][c.best][1] / c.s;
        float tw_t = logf(c.gw / abx + 1e-6f);
        tw_t = fminf(fmaxf(tw_t, -4.f), 4.f);
        float th_t = logf(c.gh / aby + 1e-6f);
        th_t = fminf(fmaxf(th_t, -4.f), 4.f);

        // jnp.remainder(v, 2pi) - pi (floor-mod, result in [0, 2pi))
        const float v = pa - c.ta + PI_F;
        const float m = v - floorf(v / TWOPI_F) * TWOPI_F;
        const float ang = m - PI_F;

        float box = smooth_l1(px - tx)
                  + smooth_l1(py - ty)
                  + smooth_l1(fminf(fmaxf(pw, -4.f), 4.f) - tw_t)
                  + smooth_l1(fminf(fmaxf(ph, -4.f), 4.f) - th_t)
                  + smooth_l1(ang);

        const float obj = softplus_f(pobj) - pobj;   // bce target 1

        local = L_BOX * box + L_OBJ * obj;
    }

    // ---- wave (64-lane) reduction, then block partial ----
    #pragma unroll
    for (int off = 32; off > 0; off >>= 1)
        local += __shfl_down(local, off, 64);

    __shared__ float wave_sum[THREADS / 64];
    const int lane = threadIdx.x & 63;
    const int wid  = threadIdx.x >> 6;
    if (lane == 0) wave_sum[wid] = local;
    __syncthreads();

    if (threadIdx.x == 0) {
        float s = 0.f;
        #pragma unroll
        for (int i = 0; i < THREADS / 64; ++i) s += wave_sum[i];
        partials[blockIdx.x] = s;
    }
}

__global__ __launch_bounds__(THREADS)
void yolo_reduce_kernel(const float* __restrict__ partials, float* __restrict__ out) {
    float s = 0.f;
    for (int i = threadIdx.x; i < BLOCKS; i += THREADS) s += partials[i];

    #pragma unroll
    for (int off = 32; off > 0; off >>= 1)
        s += __shfl_down(s, off, 64);

    __shared__ float wave_sum[THREADS / 64];
    const int lane = threadIdx.x & 63;
    const int wid  = threadIdx.x >> 6;
    if (lane == 0) wave_sum[wid] = s;
    __syncthreads();

    if (threadIdx.x == 0) {
        float t = 0.f;
        #pragma unroll
        for (int i = 0; i < THREADS / 64; ++i) t += wave_sum[i];
        out[0] = t;
    }
}

extern "C" void kernel_launch(void* const* d_in, const int* in_sizes, int n_in,
                              void* d_out, int out_size, void* d_ws, size_t ws_size,
                              hipStream_t stream) {
    // setup_inputs() dict order:
    // p0, ri0, rj0, rk0, p1, ri1, rj1, rk1, p2, ri2, rj2, rk2, boxes, labels, strides
    const float* p0 = (const float*)d_in[0];
    const int* ri0  = (const int*)d_in[1];
    const int* rj0  = (const int*)d_in[2];
    const int* rk0  = (const int*)d_in[3];
    const float* p1 = (const float*)d_in[4];
    const int* ri1  = (const int*)d_in[5];
    const int* rj1  = (const int*)d_in[6];
    const int* rk1  = (const int*)d_in[7];
    const float* p2 = (const float*)d_in[8];
    const int* ri2  = (const int*)d_in[9];
    const int* rj2  = (const int*)d_in[10];
    const int* rk2  = (const int*)d_in[11];
    const float* boxes  = (const float*)d_in[12];
    const int* labels   = (const int*)d_in[13];
    const int* strides  = (const int*)d_in[14];
    float* out      = (float*)d_out;
    float* partials = (float*)d_ws;    // BLOCKS floats, rewritten every call

    yolo_main_kernel<<<BLOCKS, THREADS, 0, stream>>>(
        p0, p1, p2,
        ri0, rj0, rk0, ri1, rj1, rk1, ri2, rj2, rk2,
        boxes, labels, strides, partials);

    yolo_reduce_kernel<<<1, THREADS, 0, stream>>>(partials, out);
}